// Round 8
// baseline (551.312 us; speedup 1.0000x reference)
//
#include <hip/hip_runtime.h>
#include <hip/hip_bf16.h>
#include <math.h>

#define B_SZ   8192
#define S_SZ   16
#define D_SZ   128
#define HID_SZ 1024
#define NUMF_SZ 103
#define GCN_SZ 40
#define G_B    4                 // batch elements per block (64 rows)
#define NBLK   (B_SZ / G_B)      // 2048 blocks
#define STRD   136               // LDS row stride (shorts), pad 8

typedef short bh8 __attribute__((ext_vector_type(8)));   // 8 bf16 (4 VGPRs)
typedef float fx4 __attribute__((ext_vector_type(4)));   // MFMA accumulator

__device__ __forceinline__ fx4 mfma16(bh8 a, bh8 b, fx4 c) {
    return __builtin_amdgcn_mfma_f32_16x16x32_bf16(a, b, c, 0, 0, 0);
}

// fp32 -> bf16 bits, round-nearest-even
__device__ __forceinline__ unsigned short f2b(float f) {
    unsigned u = __float_as_uint(f);
    return (unsigned short)((u + 0x7fffu + ((u >> 16) & 1u)) >> 16);
}
__device__ __forceinline__ float bu2f(unsigned short u) {
    return __uint_as_float(((unsigned)u) << 16);
}

// Swizzle all weights into B-fragment-linear bf16 order:
//   QKVO : [l][nt(8)][ks(4)][lane(64)][e(8)]   (nt = n/16, k = ks*32 + q*8 + e)
//   W1   : [l][nt(64)][ks(4)][lane][e]
//   W2   : [l][nt(8)][kt(32)][lane][e]
// so a wave's fragment load is one contiguous 1KB block (lane*16B).
__global__ __launch_bounds__(256) void prep_weights(
    const float* __restrict__ Wq, const float* __restrict__ Wk,
    const float* __restrict__ Wv, const float* __restrict__ Wo,
    const float* __restrict__ W1, const float* __restrict__ W2,
    unsigned short* __restrict__ WswQ, unsigned short* __restrict__ WswK,
    unsigned short* __restrict__ WswV, unsigned short* __restrict__ WswO,
    unsigned short* __restrict__ Wsw1, unsigned short* __restrict__ Wsw2,
    float* __restrict__ PEt)
{
    int i = blockIdx.x * 256 + threadIdx.x;
    if (i < 2048) {  // PE table [16][128]
        int s = i >> 7, c = i & 127;
        float expo = (float)((c >> 1) * 2) * (1.0f / 128.0f);
        float denom = powf(10000.0f, expo);
        float ang = (float)s / denom;
        PEt[i] = (c & 1) ? cosf(ang) : sinf(ang);
    }
    if (i < 2 * 16384) {   // QKVO, dst-driven
        int l = i >> 14, r = i & 16383;
        int nt = r >> 11, ks = (r >> 9) & 3, lane = (r >> 3) & 63, e = r & 7;
        int k = ks * 32 + (lane >> 4) * 8 + e;
        int n = nt * 16 + (lane & 15);
        int s = l * 16384 + k * 128 + n;
        WswQ[i] = f2b(Wq[s]); WswK[i] = f2b(Wk[s]);
        WswV[i] = f2b(Wv[s]); WswO[i] = f2b(Wo[s]);
    }
    {   // W1: src [l][k=128][n=1024]
        int l = i >> 17, r = i & 131071;
        int nt = r >> 11, ks = (r >> 9) & 3, lane = (r >> 3) & 63, e = r & 7;
        int k = ks * 32 + (lane >> 4) * 8 + e;
        int n = nt * 16 + (lane & 15);
        Wsw1[i] = f2b(W1[l * 131072 + k * 1024 + n]);
    }
    {   // W2: src [l][k=1024][n=128]
        int l = i >> 17, r = i & 131071;
        int nt = r >> 14, kt = (r >> 9) & 31, lane = (r >> 3) & 63, e = r & 7;
        int k = kt * 32 + (lane >> 4) * 8 + e;
        int n = nt * 16 + (lane & 15);
        Wsw2[i] = f2b(W2[l * 131072 + k * 128 + n]);
    }
}

// Block = 8 waves (512 thr) = 4 batch elements (64 rows). Wave w owns n-tile w
// (16 cols). LDS ~74 KB -> 2 blocks/CU = 16 waves/CU = 4 waves/SIMD.
__global__ __launch_bounds__(512, 4) void encoder_fused(
    const float* __restrict__ x, const float* __restrict__ gcn,
    const float* __restrict__ bq, const float* __restrict__ bk,
    const float* __restrict__ bv, const float* __restrict__ bo,
    const float* __restrict__ ln1g, const float* __restrict__ ln1b,
    const float* __restrict__ b1, const float* __restrict__ b2p,
    const float* __restrict__ ln2g, const float* __restrict__ ln2b,
    const float* __restrict__ Wf,
    const unsigned short* __restrict__ WswQ, const unsigned short* __restrict__ WswK,
    const unsigned short* __restrict__ WswV, const unsigned short* __restrict__ WswO,
    const unsigned short* __restrict__ Wsw1, const unsigned short* __restrict__ Wsw2,
    const float* __restrict__ PEt,
    float* __restrict__ acc1)
{
    __shared__ unsigned short ACT[64][STRD];  // activations / LN2 output
    __shared__ unsigned short Qb[64][STRD];   // Q -> ctx -> FF1 chunk
    __shared__ unsigned short Kb[64][STRD];   // K -> H (post-LN1)
    __shared__ unsigned short Vb[64][STRD];   // V
    __shared__ float LNp[64][8][2];           // per-row per-wave (sum, sumsq)
    __shared__ float LNs[64][2];              // per-row (mean, inv)
    __shared__ float redH[8];                 // head partials

    const int t = threadIdx.x;
    const int w = t >> 6, lane = t & 63;
    const int q = lane >> 4, ln = lane & 15;
    const int bbase = blockIdx.x * G_B;
    const int n = w * 16 + ln;                // this wave's output column

    // ---- load x + PE -> ACT (bf16) ----
    {
        const float4* xb = (const float4*)(x + (size_t)bbase * 2048);
        const float4* pe4 = (const float4*)PEt;
#pragma unroll
        for (int i = 0; i < 4; ++i) {
            int f4 = i * 512 + t;                  // 0..2047
            float4 xv = xb[f4];
            float4 pv = pe4[f4 & 511];
            int flat = f4 * 4;
            int row = flat >> 7, col = flat & 127;
            ushort4 pk = {f2b(xv.x + pv.x), f2b(xv.y + pv.y),
                          f2b(xv.z + pv.z), f2b(xv.w + pv.w)};
            *(ushort4*)&ACT[row][col] = pk;
        }
    }
    __syncthreads();

    for (int l = 0; l < 2; ++l) {
        // ================= QKV: wave w computes n-tile w ====================
        {
            bh8 afr[4][4];
#pragma unroll
            for (int mt = 0; mt < 4; ++mt)
#pragma unroll
                for (int ks = 0; ks < 4; ++ks)
                    afr[mt][ks] = *(const bh8*)&ACT[mt * 16 + ln][ks * 32 + q * 8];
            const unsigned short* Wm[3] = {WswQ + l * 16384, WswK + l * 16384, WswV + l * 16384};
            const float* bias3[3] = {bq + l * 128, bk + l * 128, bv + l * 128};
#pragma unroll
            for (int mtx = 0; mtx < 3; ++mtx) {
                unsigned short (*dst)[STRD] = (mtx == 0) ? Qb : (mtx == 1) ? Kb : Vb;
                bh8 wfr[4];
#pragma unroll
                for (int ks = 0; ks < 4; ++ks)
                    wfr[ks] = *(const bh8*)(Wm[mtx] + ((w * 4 + ks) * 64 + lane) * 8);
                float bb = bias3[mtx][n];
#pragma unroll
                for (int mt = 0; mt < 4; ++mt) {
                    fx4 acc = {0.f, 0.f, 0.f, 0.f};
#pragma unroll
                    for (int ks = 0; ks < 4; ++ks) acc = mfma16(afr[mt][ks], wfr[ks], acc);
#pragma unroll
                    for (int r2 = 0; r2 < 4; ++r2)
                        dst[mt * 16 + q * 4 + r2][n] = f2b(acc[r2] + bb);
                }
            }
        }
        __syncthreads();

        // ===== attention (verified raw-reshape): 2 waves per batch element ==
        // wave pair (w>>1)=batch elem; g = (w&1)*4 + q, u = ln (1 row/lane)
        {
            int base = (w >> 1) * 16;
            int g = (w & 1) * 4 + q;
            int u = ln;
            int qsr = base + 2 * g + (u >> 3), qc = (u & 7) * 16;
            float qr[16];
            {
                bh8 a0 = *(const bh8*)&Qb[qsr][qc];
                bh8 a1 = *(const bh8*)&Qb[qsr][qc + 8];
#pragma unroll
                for (int e = 0; e < 8; ++e) {
                    qr[e] = bu2f((unsigned short)a0[e]);
                    qr[8 + e] = bu2f((unsigned short)a1[e]);
                }
            }
            float p[16];
#pragma unroll
            for (int tp = 0; tp < 16; ++tp) {
                int ksr = base + 2 * g + (tp >> 3), kc = (tp & 7) * 16;
                bh8 k0 = *(const bh8*)&Kb[ksr][kc];
                bh8 k1 = *(const bh8*)&Kb[ksr][kc + 8];
                float d0 = 0.f;
#pragma unroll
                for (int e = 0; e < 8; ++e) d0 = fmaf(qr[e], bu2f((unsigned short)k0[e]), d0);
#pragma unroll
                for (int e = 0; e < 8; ++e) d0 = fmaf(qr[8 + e], bu2f((unsigned short)k1[e]), d0);
                p[tp] = d0 * 0.25f;
            }
            float mx = -1e30f;
#pragma unroll
            for (int tp = 0; tp < 16; ++tp) mx = fmaxf(mx, p[tp]);
            float sum = 0.f;
#pragma unroll
            for (int tp = 0; tp < 16; ++tp) { p[tp] = __expf(p[tp] - mx); sum += p[tp]; }
            float is = 1.0f / sum;
#pragma unroll
            for (int tp = 0; tp < 16; ++tp) p[tp] *= is;
            float ctx[16];
#pragma unroll
            for (int e = 0; e < 16; ++e) ctx[e] = 0.f;
#pragma unroll
            for (int tp = 0; tp < 16; ++tp) {
                int vsr = base + 2 * g + (tp >> 3), vc = (tp & 7) * 16;
                bh8 v0 = *(const bh8*)&Vb[vsr][vc];
                bh8 v1 = *(const bh8*)&Vb[vsr][vc + 8];
#pragma unroll
                for (int e = 0; e < 8; ++e) ctx[e] = fmaf(p[tp], bu2f((unsigned short)v0[e]), ctx[e]);
#pragma unroll
                for (int e = 0; e < 8; ++e) ctx[8 + e] = fmaf(p[tp], bu2f((unsigned short)v1[e]), ctx[8 + e]);
            }
            __syncthreads();   // Qb reads (qr) complete block-wide before overwrite
            bh8 c0, c1;
#pragma unroll
            for (int e = 0; e < 8; ++e) {
                c0[e] = (short)f2b(ctx[e]);
                c1[e] = (short)f2b(ctx[8 + e]);
            }
            *(bh8*)&Qb[qsr][qc] = c0;
            *(bh8*)&Qb[qsr][qc + 8] = c1;
        }
        __syncthreads();

        // ================= O-proj + residual + LN1 -> Kb (H) ================
        fx4 Cv[4];
        {
            bh8 cfr[4][4];
#pragma unroll
            for (int mt = 0; mt < 4; ++mt)
#pragma unroll
                for (int ks = 0; ks < 4; ++ks)
                    cfr[mt][ks] = *(const bh8*)&Qb[mt * 16 + ln][ks * 32 + q * 8];
            bh8 wfr[4];
#pragma unroll
            for (int ks = 0; ks < 4; ++ks)
                wfr[ks] = *(const bh8*)(WswO + l * 16384 + ((w * 4 + ks) * 64 + lane) * 8);
            float bb = bo[l * 128 + n];
#pragma unroll
            for (int mt = 0; mt < 4; ++mt) {
                fx4 acc = {0.f, 0.f, 0.f, 0.f};
#pragma unroll
                for (int ks = 0; ks < 4; ++ks) acc = mfma16(cfr[mt][ks], wfr[ks], acc);
#pragma unroll
                for (int r2 = 0; r2 < 4; ++r2)
                    Cv[mt][r2] = acc[r2] + bb + bu2f(ACT[mt * 16 + q * 4 + r2][n]);
            }
        }
        // LN1 partials (16-lane butterfly within this wave's 16 cols)
#pragma unroll
        for (int mt = 0; mt < 4; ++mt) {
            float s4[4], v4[4];
#pragma unroll
            for (int r2 = 0; r2 < 4; ++r2) {
                float a0 = Cv[mt][r2];
                float s = a0, v = a0 * a0;
#pragma unroll
                for (int m = 1; m < 16; m <<= 1) { s += __shfl_xor(s, m); v += __shfl_xor(v, m); }
                s4[r2] = s; v4[r2] = v;
            }
            if (ln < 8)
                LNp[mt * 16 + q * 4 + (ln >> 1)][w][ln & 1] = (ln & 1) ? v4[ln >> 1] : s4[ln >> 1];
        }
        __syncthreads();
        if (t < 64) {
            float s = 0.f, v = 0.f;
#pragma unroll
            for (int ww = 0; ww < 8; ++ww) { s += LNp[t][ww][0]; v += LNp[t][ww][1]; }
            float mean = s * (1.0f / 128.0f);
            LNs[t][0] = mean;
            LNs[t][1] = rsqrtf(v * (1.0f / 128.0f) - mean * mean + 1e-5f);
        }
        __syncthreads();
        {
            float gg = ln1g[l * 128 + n], be = ln1b[l * 128 + n];
#pragma unroll
            for (int mt = 0; mt < 4; ++mt)
#pragma unroll
                for (int r2 = 0; r2 < 4; ++r2) {
                    int row = mt * 16 + q * 4 + r2;
                    Kb[row][n] = f2b((Cv[mt][r2] - LNs[row][0]) * LNs[row][1] * gg + be);
                }
        }
        __syncthreads();

        // ================= FF (8 chunks of 128 hidden) ======================
        bh8 hfr[4][4];
#pragma unroll
        for (int mt = 0; mt < 4; ++mt)
#pragma unroll
            for (int ks = 0; ks < 4; ++ks)
                hfr[mt][ks] = *(const bh8*)&Kb[mt * 16 + ln][ks * 32 + q * 8];
        fx4 f2a[4];
#pragma unroll
        for (int mt = 0; mt < 4; ++mt) f2a[mt] = fx4{0.f, 0.f, 0.f, 0.f};
        for (int ch = 0; ch < 8; ++ch) {
            bh8 w1fr[4];
            {
                int ntg = ch * 8 + w;
#pragma unroll
                for (int ks = 0; ks < 4; ++ks)
                    w1fr[ks] = *(const bh8*)(Wsw1 + l * 131072 + ((ntg * 4 + ks) * 64 + lane) * 8);
            }
            float bb = b1[l * HID_SZ + ch * 128 + n];
#pragma unroll
            for (int mt = 0; mt < 4; ++mt) {
                fx4 acc = {0.f, 0.f, 0.f, 0.f};
#pragma unroll
                for (int ks = 0; ks < 4; ++ks) acc = mfma16(hfr[mt][ks], w1fr[ks], acc);
#pragma unroll
                for (int r2 = 0; r2 < 4; ++r2) {
                    float vv = acc[r2] + bb;
                    Qb[mt * 16 + q * 4 + r2][n] = f2b(vv > 0.f ? vv : 0.f);
                }
            }
            __syncthreads();
            bh8 w2fr[4];
#pragma unroll
            for (int ks = 0; ks < 4; ++ks)
                w2fr[ks] = *(const bh8*)(Wsw2 + l * 131072 +
                    ((w * 32 + ch * 4 + ks) * 64 + lane) * 8);
#pragma unroll
            for (int mt = 0; mt < 4; ++mt) {
                bh8 ffr[4];
#pragma unroll
                for (int ks = 0; ks < 4; ++ks)
                    ffr[ks] = *(const bh8*)&Qb[mt * 16 + ln][ks * 32 + q * 8];
#pragma unroll
                for (int ks = 0; ks < 4; ++ks)
                    f2a[mt] = mfma16(ffr[ks], w2fr[ks], f2a[mt]);
            }
            __syncthreads();
        }
        // epilogue: + b2 + H residual, LN2 -> ACT
        fx4 Cv2[4];
        {
            float bb = b2p[l * 128 + n];
#pragma unroll
            for (int mt = 0; mt < 4; ++mt)
#pragma unroll
                for (int r2 = 0; r2 < 4; ++r2)
                    Cv2[mt][r2] = f2a[mt][r2] + bb + bu2f(Kb[mt * 16 + q * 4 + r2][n]);
        }
#pragma unroll
        for (int mt = 0; mt < 4; ++mt) {
            float s4[4], v4[4];
#pragma unroll
            for (int r2 = 0; r2 < 4; ++r2) {
                float a0 = Cv2[mt][r2];
                float s = a0, v = a0 * a0;
#pragma unroll
                for (int m = 1; m < 16; m <<= 1) { s += __shfl_xor(s, m); v += __shfl_xor(v, m); }
                s4[r2] = s; v4[r2] = v;
            }
            if (ln < 8)
                LNp[mt * 16 + q * 4 + (ln >> 1)][w][ln & 1] = (ln & 1) ? v4[ln >> 1] : s4[ln >> 1];
        }
        __syncthreads();
        if (t < 64) {
            float s = 0.f, v = 0.f;
#pragma unroll
            for (int ww = 0; ww < 8; ++ww) { s += LNp[t][ww][0]; v += LNp[t][ww][1]; }
            float mean = s * (1.0f / 128.0f);
            LNs[t][0] = mean;
            LNs[t][1] = rsqrtf(v * (1.0f / 128.0f) - mean * mean + 1e-5f);
        }
        __syncthreads();
        {
            float gg = ln2g[l * 128 + n], be = ln2b[l * 128 + n];
#pragma unroll
            for (int mt = 0; mt < 4; ++mt)
#pragma unroll
                for (int r2 = 0; r2 < 4; ++r2) {
                    int row = mt * 16 + q * 4 + r2;
                    ACT[row][n] = f2b((Cv2[mt][r2] - LNs[row][0]) * LNs[row][1] * gg + be);
                }
        }
        __syncthreads();
    }

    // ======= head partial dot: 2 waves per batch element ===================
    {
        int bl = w >> 1;
        int bg = bbase + bl;
        float part = 0.f;
        int srow = lane >> 2, c0 = (lane & 3) * 32 + (w & 1) * 16;
#pragma unroll
        for (int i = 0; i < 2; ++i) {
            bh8 av = *(const bh8*)&ACT[bl * 16 + srow][c0 + i * 8];
            int fl = srow * 128 + c0 + i * 8;
#pragma unroll
            for (int e = 0; e < 8; ++e)
                part = fmaf(bu2f((unsigned short)av[e]), Wf[fl + e], part);
        }
        if ((w & 1) == 0 && lane < GCN_SZ)
            part = fmaf(gcn[(size_t)bg * GCN_SZ + lane], Wf[2048 + lane], part);
#pragma unroll
        for (int off = 32; off; off >>= 1) part += __shfl_xor(part, off);
        if (lane == 0) redH[w] = part;
    }
    __syncthreads();
    if (t < G_B) acc1[bbase + t] = redH[2 * t] + redH[2 * t + 1];
}

// BN batch statistics: per-column sum / sumsq of n = num @ Wn + bnum.
__global__ __launch_bounds__(256) void num_stats_kernel(
    const float* __restrict__ num, const float* __restrict__ Wn,
    const float* __restrict__ bnum,
    float* __restrict__ ssum, float* __restrict__ ssq)
{
    __shared__ float NUM[16][NUMF_SZ + 1];
    __shared__ float cred[4][128];
    const int t = threadIdx.x;
    const int b0 = blockIdx.x * 16;
    const int j = t & 127, sg = t >> 7, s0 = sg * 8;

    for (int idx = t; idx < 16 * NUMF_SZ; idx += 256) {
        int r = idx / NUMF_SZ, f = idx - r * NUMF_SZ;
        NUM[r][f] = num[(size_t)(b0 + r) * NUMF_SZ + f];
    }
    __syncthreads();

    float acc[8];
    float bnv = bnum[j];
#pragma unroll
    for (int r = 0; r < 8; ++r) acc[r] = bnv;
    for (int f = 0; f < NUMF_SZ; ++f) {
        float w = Wn[f * 128 + j];
#pragma unroll
        for (int r = 0; r < 8; ++r) acc[r] = fmaf(NUM[s0 + r][f], w, acc[r]);
    }
    float lsum = 0.f, lsq = 0.f;
#pragma unroll
    for (int r = 0; r < 8; ++r) {
        lsum += acc[r];
        lsq = fmaf(acc[r], acc[r], lsq);
    }
    cred[sg][j] = lsum;
    cred[2 + sg][j] = lsq;
    __syncthreads();
    if (sg == 0) atomicAdd(&ssum[j], cred[0][j] + cred[1][j]);
    else         atomicAdd(&ssq[j],  cred[2][j] + cred[3][j]);
}

// Recompute n for 8 batch elems/block, BN, final dot + sigmoid.
__global__ __launch_bounds__(128) void final_kernel(
    const float* __restrict__ num, const float* __restrict__ Wn,
    const float* __restrict__ bnum,
    const float* __restrict__ ssum, const float* __restrict__ ssq,
    const float* __restrict__ gamma, const float* __restrict__ beta,
    const float* __restrict__ Wf, const float* __restrict__ bfin,
    const float* __restrict__ acc1, float* __restrict__ out)
{
    const int b0 = blockIdx.x * 8, jj = threadIdx.x;
    __shared__ float NUMr[8][NUMF_SZ];
    __shared__ float redF[2][8];
    for (int idx = jj; idx < 8 * NUMF_SZ; idx += 128) {
        int r = idx / NUMF_SZ, f = idx - r * NUMF_SZ;
        NUMr[r][f] = num[(size_t)(b0 + r) * NUMF_SZ + f];
    }
    __syncthreads();

    float nv[8];
    float bn = bnum[jj];
#pragma unroll
    for (int r = 0; r < 8; ++r) nv[r] = bn;
    for (int f = 0; f < NUMF_SZ; ++f) {
        float wv = Wn[f * 128 + jj];
#pragma unroll
        for (int r = 0; r < 8; ++r) nv[r] = fmaf(NUMr[r][f], wv, nv[r]);
    }
    float mean = ssum[jj] * (1.0f / (float)B_SZ);
    float var = ssq[jj] * (1.0f / (float)B_SZ) - mean * mean;
    float scale = rsqrtf(var + 1e-5f) * gamma[jj];
    float bet = beta[jj];
    float wf = Wf[2088 + jj];
    float v[8];
#pragma unroll
    for (int r = 0; r < 8; ++r) v[r] = ((nv[r] - mean) * scale + bet) * wf;
#pragma unroll
    for (int off = 32; off; off >>= 1)
#pragma unroll
        for (int r = 0; r < 8; ++r) v[r] += __shfl_xor(v[r], off);
    if ((jj & 63) == 0)
#pragma unroll
        for (int r = 0; r < 8; ++r) redF[jj >> 6][r] = v[r];
    __syncthreads();
    if (jj < 8) {
        float z = acc1[b0 + jj] + redF[0][jj] + redF[1][jj] + bfin[0];
        out[b0 + jj] = 1.0f / (1.0f + __expf(-z));
    }
}

extern "C" void kernel_launch(void* const* d_in, const int* in_sizes, int n_in,
                              void* d_out, int out_size, void* d_ws, size_t ws_size,
                              hipStream_t stream)
{
    const float* x    = (const float*)d_in[0];
    const float* gcn  = (const float*)d_in[1];
    const float* num  = (const float*)d_in[2];
    const float* Wq   = (const float*)d_in[3];
    const float* bq   = (const float*)d_in[4];
    const float* Wk   = (const float*)d_in[5];
    const float* bk   = (const float*)d_in[6];
    const float* Wv   = (const float*)d_in[7];
    const float* bv   = (const float*)d_in[8];
    const float* Wo   = (const float*)d_in[9];
    const float* bo   = (const float*)d_in[10];
    const float* ln1g = (const float*)d_in[11];
    const float* ln1b = (const float*)d_in[12];
    const float* W1   = (const float*)d_in[13];
    const float* b1   = (const float*)d_in[14];
    const float* W2   = (const float*)d_in[15];
    const float* b2p  = (const float*)d_in[16];
    const float* ln2g = (const float*)d_in[17];
    const float* ln2b = (const float*)d_in[18];
    const float* Wn   = (const float*)d_in[19];
    const float* bnum = (const float*)d_in[20];
    const float* bng  = (const float*)d_in[21];
    const float* bnb  = (const float*)d_in[22];
    const float* Wf   = (const float*)d_in[23];
    const float* bfin = (const float*)d_in[24];

    // ws: acc1 (8192 f32) | ssum | ssq | pad to 40960 B | swizzled bf16 weights | PE
    float* acc1 = (float*)d_ws;
    float* ssum = acc1 + B_SZ;
    float* ssq  = ssum + 128;
    unsigned short* wb = (unsigned short*)((char*)d_ws + 40960);
    unsigned short* WswQ = wb;
    unsigned short* WswK = wb + 32768;
    unsigned short* WswV = wb + 65536;
    unsigned short* WswO = wb + 98304;
    unsigned short* Wsw1 = wb + 131072;
    unsigned short* Wsw2 = wb + 393216;
    float* PEt = (float*)((char*)d_ws + 40960 + 1310720);

    hipMemsetAsync(ssum, 0, 2 * 128 * sizeof(float), stream);
    prep_weights<<<1024, 256, 0, stream>>>(Wq, Wk, Wv, Wo, W1, W2,
        WswQ, WswK, WswV, WswO, Wsw1, Wsw2, PEt);
    encoder_fused<<<NBLK, 512, 0, stream>>>(x, gcn, bq, bk, bv, bo,
        ln1g, ln1b, b1, b2p, ln2g, ln2b, Wf,
        WswQ, WswK, WswV, WswO, Wsw1, Wsw2, PEt, acc1);
    num_stats_kernel<<<B_SZ / 16, 256, 0, stream>>>(num, Wn, bnum, ssum, ssq);
    final_kernel<<<B_SZ / 8, 128, 0, stream>>>(num, Wn, bnum, ssum, ssq, bng, bnb,
        Wf, bfin, acc1, (float*)d_out);
}